// Round 14
// baseline (87.958 us; speedup 1.0000x reference)
//
#include <hip/hip_runtime.h>
#include <hip/hip_bf16.h>
#include <cstdint>

typedef float f32x4 __attribute__((ext_vector_type(4)));
typedef float f32x16 __attribute__((ext_vector_type(16)));
typedef short s16x8 __attribute__((ext_vector_type(8)));
typedef short s16x4 __attribute__((ext_vector_type(4)));
typedef unsigned int u32x2 __attribute__((ext_vector_type(2)));
typedef unsigned int u32x4 __attribute__((ext_vector_type(4)));

constexpr int B_ = 2, L_ = 2048, D_ = 1024, H_ = 16, DH = 64, HALF = 64;
constexpr int M_ROWS = B_ * L_;   // 4096
constexpr int QKV_N = 3 * D_;     // 3072

__device__ __forceinline__ void gload16(const void* g, void* l) {
    __builtin_amdgcn_global_load_lds(
        (const __attribute__((address_space(1))) unsigned int*)g,
        (__attribute__((address_space(3))) unsigned int*)l, 16, 0, 0);
}

__device__ __forceinline__ void cfence() {
    __builtin_amdgcn_sched_barrier(0);
    asm volatile("" ::: "memory");
}

// ---------------- fused prep: weight cvt 64B/thread (blocks 0..1023) + RMSNorm (1024..2047) ----------------
__global__ __launch_bounds__(256) void prep_kernel(const float* __restrict__ x,
                                                   const float* __restrict__ wn,
                                                   const float* __restrict__ wq,
                                                   const float* __restrict__ wo,
                                                   __hip_bfloat16* __restrict__ xn,
                                                   __hip_bfloat16* __restrict__ oq,
                                                   __hip_bfloat16* __restrict__ oo) {
    constexpr int NQ16 = QKV_N * D_ / 16;            // 196608 (16 floats per thread)
    constexpr int NCVT16 = NQ16 + D_ * D_ / 16;      // 262144
    constexpr int CVTBLK = NCVT16 / 256;             // 1024
    int bid = blockIdx.x;
    int tid = threadIdx.x;
    if (bid < CVTBLK) {
        int i = bid * 256 + tid;
        const float* src; __hip_bfloat16* dst; int j;
        if (i < NQ16) { src = wq; dst = oq; j = i; }
        else          { src = wo; dst = oo; j = i - NQ16; }
        const float4* s4 = reinterpret_cast<const float4*>(src) + (size_t)j * 4;
        float4 v[4];
#pragma unroll
        for (int c = 0; c < 4; ++c) v[c] = s4[c];
        s16x8 p0, p1;
#pragma unroll
        for (int c = 0; c < 2; ++c) {
            float vals[8] = {v[2*c].x, v[2*c].y, v[2*c].z, v[2*c].w,
                             v[2*c+1].x, v[2*c+1].y, v[2*c+1].z, v[2*c+1].w};
            s16x8 pk;
#pragma unroll
            for (int e = 0; e < 8; ++e) {
                __hip_bfloat16 t = __float2bfloat16(vals[e]);
                pk[e] = *reinterpret_cast<short*>(&t);
            }
            if (c == 0) p0 = pk; else p1 = pk;
        }
        __hip_bfloat16* o = dst + (size_t)j * 16;
        *(s16x8*)(o) = p0;
        *(s16x8*)(o + 8) = p1;
    } else {
        int w = tid >> 6, lane = tid & 63;
        int row = (bid - CVTBLK) * 4 + w;
        const float4* xr = reinterpret_cast<const float4*>(x + (size_t)row * D_);
        const float4* wr = reinterpret_cast<const float4*>(wn);
        float4 v[4];
        float ss = 0.f;
#pragma unroll
        for (int c = 0; c < 4; ++c) {
            v[c] = xr[c * 64 + lane];
            ss += v[c].x * v[c].x + v[c].y * v[c].y + v[c].z * v[c].z + v[c].w * v[c].w;
        }
#pragma unroll
        for (int off = 32; off; off >>= 1) ss += __shfl_xor(ss, off);
        float rinv = rsqrtf(ss * (1.0f / D_) + 1e-6f);
#pragma unroll
        for (int c = 0; c < 4; ++c) {
            float4 wv = wr[c * 64 + lane];
            s16x4 pk;
            float vals[4] = {v[c].x * rinv * wv.x, v[c].y * rinv * wv.y,
                             v[c].z * rinv * wv.z, v[c].w * rinv * wv.w};
#pragma unroll
            for (int e = 0; e < 4; ++e) {
                __hip_bfloat16 t = __float2bfloat16(vals[e]);
                pk[e] = *reinterpret_cast<short*>(&t);
            }
            *(s16x4*)(xn + (size_t)row * D_ + (c * 64 + lane) * 4) = pk;
        }
    }
}

// ---------------- QKV GEMM: 128x128, BK=32, 2 buffers = 32KB LDS, 3 blocks/CU ----------------
// 256 thr / 4 waves (2x2), wave tile 64x64. r7-proven schedule: STG(t+1) -> vmcnt(4)
// [own tile-t retired, t+1 in flight] -> barrier -> reads -> 16 MFMA -> lgkmcnt(0)
// -> barrier. Occupancy does the overlap (m114): 3 co-resident blocks/CU.
// LDS pair-packed rows (r9-verified): LDS-row R slot s holds M[2R+(u>>2)][(u&3)*8], u=s^(R&7).
// Epilogue: q,k direct stores; v -> 2-pass 64-col LDS transpose -> vT.
__global__ __launch_bounds__(256, 3) void gemm_qkv_kernel(const __hip_bfloat16* __restrict__ A,
                                                          const __hip_bfloat16* __restrict__ Bt,
                                                          __hip_bfloat16* __restrict__ Cbf,
                                                          __hip_bfloat16* __restrict__ vT,
                                                          int M, int N, int K) {
    constexpr int BOFF = 8192;                 // B region within buffer
    constexpr int BUFB = 16384;
    constexpr int NT = 32;                     // K=1024 / BK=32
    __shared__ __align__(16) char smem[2 * BUFB];   // 32 KB

    const int tid = threadIdx.x;
    const int lane = tid & 63;
    const int wid = tid >> 6;

    // XCD-aware bijective swizzle (nwg = 768, % 8 == 0)
    int nwg = gridDim.x * gridDim.y;
    int lin = blockIdx.y * gridDim.x + blockIdx.x;
    int cpx = nwg >> 3;
    int swz = (lin & 7) * cpx + (lin >> 3);
    int bx = swz % gridDim.x;
    int by = swz / gridDim.x;

    const int rowBase = by * 128;
    const int colBase = bx * 128;

    // staging maps (pair-packed rows): thread t -> LDS bytes issueBase + t*16
    const int sR = tid >> 3;                   // LDS row within 4KB issue (0..31)
    const int su = (tid & 7) ^ (sR & 7);
    const int sMrow = 2 * sR + (su >> 2);      // matrix row 0..63 within issue
    const int sCol = (su & 3) * 8;
    const __hip_bfloat16* aG0 = A + (size_t)(rowBase + sMrow) * K + sCol;
    const __hip_bfloat16* aG1 = aG0 + (size_t)64 * K;
    const __hip_bfloat16* bG0 = Bt + (size_t)(colBase + sMrow) * K + sCol;
    const __hip_bfloat16* bG1 = bG0 + (size_t)64 * K;
    const int dstW = wid << 10;                // + lane*16 by HW

    // fragment read coords (r9-verified roundtrip)
    const int wm = wid >> 1, wn = wid & 1;
    const int l15 = lane & 15, hi = lane >> 4;
    const int sRd = (((l15 & 1) << 2) | hi) ^ ((l15 >> 1) & 7);
    const int aRd = wm * 4096 + (l15 >> 1) * 128 + sRd * 16;          // + mf*1024
    const int bRd = BOFF + wn * 4096 + (l15 >> 1) * 128 + sRd * 16;   // + nf*1024

    f32x4 acc[4][4];
#pragma unroll
    for (int m = 0; m < 4; ++m)
#pragma unroll
        for (int n = 0; n < 4; ++n) acc[m][n] = (f32x4){0.f, 0.f, 0.f, 0.f};

    auto STG = [&](int tt) {
        char* base = smem + (tt & 1) * BUFB;
        gload16(aG0 + (size_t)tt * 32, base + dstW);
        gload16(aG1 + (size_t)tt * 32, base + 4096 + dstW);
        gload16(bG0 + (size_t)tt * 32, base + BOFF + dstW);
        gload16(bG1 + (size_t)tt * 32, base + BOFF + 4096 + dstW);
    };

    STG(0);

    for (int t = 0; t < NT; ++t) {
        if (t + 1 < NT) {
            STG(t + 1);
            asm volatile("s_waitcnt vmcnt(4)" ::: "memory");   // tile t landed
        } else {
            asm volatile("s_waitcnt vmcnt(0)" ::: "memory");
        }
        __builtin_amdgcn_s_barrier();           // all waves: tile t in LDS
        cfence();

        const char* tb = smem + (t & 1) * BUFB;
        s16x8 af[4], bf[4];
#pragma unroll
        for (int mf = 0; mf < 4; ++mf)
            af[mf] = *(const s16x8*)(tb + aRd + mf * 1024);
#pragma unroll
        for (int nf = 0; nf < 4; ++nf)
            bf[nf] = *(const s16x8*)(tb + bRd + nf * 1024);

        __builtin_amdgcn_s_setprio(1);
#pragma unroll
        for (int mf = 0; mf < 4; ++mf)
#pragma unroll
            for (int nf = 0; nf < 4; ++nf)
                acc[mf][nf] = __builtin_amdgcn_mfma_f32_16x16x32_bf16(af[mf], bf[nf],
                                                                      acc[mf][nf], 0, 0, 0);
        __builtin_amdgcn_s_setprio(0);

        asm volatile("s_waitcnt lgkmcnt(0)" ::: "memory");   // reads done before overwrite
        __builtin_amdgcn_s_barrier();
        cfence();
    }

    if (colBase < 2 * D_) {                     // q,k section: direct stores
#pragma unroll
        for (int mf = 0; mf < 4; ++mf)
#pragma unroll
            for (int nf = 0; nf < 4; ++nf) {
                int col = colBase + wn * 64 + nf * 16 + l15;
                int row0 = rowBase + wm * 64 + mf * 16 + 4 * hi;
#pragma unroll
                for (int r = 0; r < 4; ++r)
                    Cbf[(size_t)(row0 + r) * N + col] = __float2bfloat16(acc[mf][nf][r]);
            }
    } else {                                    // v section: 2-pass 64-col LDS transpose
        __syncthreads();                        // main-loop LDS traffic done
        int bb2 = rowBase >> 11, i0 = rowBase & (L_ - 1);
        char* Ct = smem;                        // [64 cols][stride 272B] = 17408 B
#pragma unroll
        for (int p = 0; p < 2; ++p) {
            if (p) __syncthreads();             // pass-0 reads done before overwrite
            if (wn == p) {
#pragma unroll
                for (int mf = 0; mf < 4; ++mf)
#pragma unroll
                    for (int nf = 0; nf < 4; ++nf) {
                        int cl = nf * 16 + l15;
                        int rlb = wm * 64 + mf * 16 + 4 * hi;
                        s16x4 pk;
#pragma unroll
                        for (int r = 0; r < 4; ++r) {
                            __hip_bfloat16 t = __float2bfloat16(acc[mf][nf][r]);
                            pk[r] = *reinterpret_cast<short*>(&t);
                        }
                        *(s16x4*)(Ct + cl * 272 + rlb * 2) = pk;
                    }
            }
            __syncthreads();
            {
                int c = tid >> 2, qd = tid & 3;          // col 0..63, quarter 0..3
                int gcol = colBase + p * 64 + c - 2 * D_;
                int hh = gcol >> 6, dd = gcol & 63;
                __hip_bfloat16* dstp = vT + ((size_t)(bb2 * H_ + hh) * DH + dd) * L_ + i0;
#pragma unroll
                for (int ch = 0; ch < 4; ++ch) {
                    int rr = qd * 32 + ch * 8;
                    *(s16x8*)(dstp + rr) = *(const s16x8*)(Ct + c * 272 + rr * 2);
                }
            }
        }
    }
}

// ---------------- out-proj GEMM (r7/r8 proven): 128 x 64 tile, BK=64, 2 buffers ----------------
__global__ __launch_bounds__(256, 2) void gemm_proj_kernel(const __hip_bfloat16* __restrict__ A,
                                                           const __hip_bfloat16* __restrict__ Bt,
                                                           float* __restrict__ Cf,
                                                           const float* __restrict__ resid,
                                                           int M, int N, int K) {
    constexpr int BM = 128, BN = 64;
    constexpr int ABYTES = BM * 128;           // 16384
    constexpr int BBYTES = BN * 128;           // 8192
    constexpr int BUF = ABYTES + BBYTES;       // 24576
    __shared__ __align__(16) char smem[2 * BUF];   // 48 KB

    const int tid = threadIdx.x;
    const int lane = tid & 63;
    const int wid = tid >> 6;

    int nwg = gridDim.x * gridDim.y;
    int lin = blockIdx.y * gridDim.x + blockIdx.x;
    int cpx = nwg >> 3;
    int swz = (lin & 7) * cpx + (lin >> 3);
    int bx = swz % gridDim.x;
    int by = swz / gridDim.x;

    const int rowBase = by * BM;
    const int colBase = bx * BN;
    const int NTILES = K >> 6;

    const int srow = tid >> 3;                  // 0..31
    const int colSw = ((tid & 7) ^ (srow & 7)) << 3;
    const __hip_bfloat16* aG = A + (size_t)(rowBase + srow) * K + colSw;
    const __hip_bfloat16* bG = Bt + (size_t)(colBase + srow) * K + colSw;
    const int dstW = wid << 10;

    const int wm = wid >> 1, wn = wid & 1;
    const int l15 = lane & 15, hi = lane >> 4;
    const int s7 = l15 & 7;
    const int rA = wm * 64 + l15;
    const int rB = wn * 32 + l15;

    f32x4 acc[4][2];
#pragma unroll
    for (int m = 0; m < 4; ++m)
#pragma unroll
        for (int n = 0; n < 2; ++n) acc[m][n] = (f32x4){0.f, 0.f, 0.f, 0.f};

#pragma unroll
    for (int i = 0; i < 4; ++i) gload16(aG + (size_t)(i * 32) * K, smem + i * 4096 + dstW);
#pragma unroll
    for (int i = 0; i < 2; ++i) gload16(bG + (size_t)(i * 32) * K, smem + ABYTES + i * 4096 + dstW);

    for (int kt = 0; kt < NTILES; ++kt) {
        const int bf_ = kt & 1;
        if (kt + 1 < NTILES) {
            char* base = smem + (bf_ ^ 1) * BUF;
            const __hip_bfloat16* as = aG + (size_t)(kt + 1) * 64;
            const __hip_bfloat16* bs = bG + (size_t)(kt + 1) * 64;
#pragma unroll
            for (int i = 0; i < 4; ++i) gload16(as + (size_t)(i * 32) * K, base + i * 4096 + dstW);
#pragma unroll
            for (int i = 0; i < 2; ++i) gload16(bs + (size_t)(i * 32) * K, base + ABYTES + i * 4096 + dstW);
            asm volatile("s_waitcnt vmcnt(6)" ::: "memory");
        } else {
            asm volatile("s_waitcnt vmcnt(0)" ::: "memory");
        }
        __builtin_amdgcn_s_barrier();
        cfence();

        const char* ab = smem + bf_ * BUF;
        const char* bb = ab + ABYTES;
        s16x8 af[4][2], bfr[2][2];
#pragma unroll
        for (int mf = 0; mf < 4; ++mf)
#pragma unroll
            for (int kk = 0; kk < 2; ++kk)
                af[mf][kk] = *(const s16x8*)(ab + (rA + mf * 16) * 128 + (((kk * 4 + hi) ^ s7) << 4));
#pragma unroll
        for (int nf = 0; nf < 2; ++nf)
#pragma unroll
            for (int kk = 0; kk < 2; ++kk)
                bfr[nf][kk] = *(const s16x8*)(bb + (rB + nf * 16) * 128 + (((kk * 4 + hi) ^ s7) << 4));

        __builtin_amdgcn_s_setprio(1);
#pragma unroll
        for (int kk = 0; kk < 2; ++kk)
#pragma unroll
            for (int mf = 0; mf < 4; ++mf)
#pragma unroll
                for (int nf = 0; nf < 2; ++nf)
                    acc[mf][nf] = __builtin_amdgcn_mfma_f32_16x16x32_bf16(af[mf][kk], bfr[nf][kk],
                                                                          acc[mf][nf], 0, 0, 0);
        __builtin_amdgcn_s_setprio(0);

        asm volatile("s_waitcnt lgkmcnt(0)" ::: "memory");
        __builtin_amdgcn_s_barrier();
        cfence();
    }

#pragma unroll
    for (int mf = 0; mf < 4; ++mf)
#pragma unroll
        for (int nf = 0; nf < 2; ++nf) {
            int col = colBase + wn * 32 + nf * 16 + l15;
            int row0 = rowBase + wm * 64 + mf * 16 + 4 * hi;
#pragma unroll
            for (int r = 0; r < 4; ++r)
                Cf[(size_t)(row0 + r) * N + col] = acc[mf][nf][r] + resid[(size_t)(row0 + r) * N + col];
        }
}

// ---------------- barrier-free LDS-free MFMA banded attention (round-8, proven) ----------------
__global__ __launch_bounds__(128, 2) void attn_mfma_kernel(const __hip_bfloat16* __restrict__ qkv,
                                                           const __hip_bfloat16* __restrict__ vT,
                                                           __hip_bfloat16* __restrict__ attn) {
    int tid = threadIdx.x;
    int w = tid >> 6;
    int lane = tid & 63;
    int l31 = lane & 31, hi1 = lane >> 5;
    int tq = blockIdx.x, h = blockIdx.y, b = blockIdx.z;
    int qbase = tq * 64 + 32 * w;
    int kb = qbase - HALF;
    int qg = qbase + l31;
    const __hip_bfloat16* qkvb = qkv + (size_t)(b * L_) * QKV_N;
    const __hip_bfloat16* vTg = vT + (size_t)(b * H_ + h) * DH * L_;

    s16x8 qf[4];
#pragma unroll
    for (int kk = 0; kk < 4; ++kk)
        qf[kk] = *(const s16x8*)(qkvb + (size_t)qg * QKV_N + h * DH + kk * 16 + hi1 * 8);

    f32x16 T[5];
#pragma unroll
    for (int kt = 0; kt < 5; ++kt) T[kt] = (f32x16)(0.f);
#pragma unroll
    for (int kt = 0; kt < 5; ++kt) {
        int keyg = kb + 32 * kt + l31;
        int kc = keyg < 0 ? 0 : (keyg > L_ - 1 ? L_ - 1 : keyg);
        const __hip_bfloat16* kp = qkvb + (size_t)kc * QKV_N + D_ + h * DH + hi1 * 8;
#pragma unroll
        for (int kk = 0; kk < 4; ++kk) {
            s16x8 kf = *(const s16x8*)(kp + kk * 16);
            T[kt] = __builtin_amdgcn_mfma_f32_32x32x16_bf16(kf, qf[kk], T[kt], 0, 0, 0);
        }
    }

    float mx = -1e30f;
#pragma unroll
    for (int kt = 0; kt < 5; ++kt) {
#pragma unroll
        for (int r = 0; r < 16; ++r) {
            int koff = (r & 3) + 8 * (r >> 2) + 4 * hi1;
            int keyg = kb + 32 * kt + koff;
            int del = keyg - qg;
            bool ok = (del >= -HALF) && (del <= HALF) && (keyg >= 0) && (keyg < L_);
            float t = ok ? T[kt][r] * 0.125f : -1e30f;
            T[kt][r] = t;
            mx = fmaxf(mx, t);
        }
    }
    mx = fmaxf(mx, __shfl_xor(mx, 32));
    float sum = 0.f;
#pragma unroll
    for (int kt = 0; kt < 5; ++kt) {
#pragma unroll
        for (int r = 0; r < 16; ++r) {
            float p = __expf(T[kt][r] - mx);
            T[kt][r] = p;
            sum += p;
        }
    }
    sum += __shfl_xor(sum, 32);
    float inv = 1.0f / sum;

    u32x4 pu[10];
#pragma unroll
    for (int kt = 0; kt < 5; ++kt) {
#pragma unroll
        for (int s = 0; s < 2; ++s) {
            unsigned P0, P1, P2, P3;
            asm("v_cvt_pk_bf16_f32 %0, %1, %2" : "=v"(P0) : "v"(T[kt][8 * s + 0]), "v"(T[kt][8 * s + 1]));
            asm("v_cvt_pk_bf16_f32 %0, %1, %2" : "=v"(P1) : "v"(T[kt][8 * s + 2]), "v"(T[kt][8 * s + 3]));
            asm("v_cvt_pk_bf16_f32 %0, %1, %2" : "=v"(P2) : "v"(T[kt][8 * s + 4]), "v"(T[kt][8 * s + 5]));
            asm("v_cvt_pk_bf16_f32 %0, %1, %2" : "=v"(P3) : "v"(T[kt][8 * s + 6]), "v"(T[kt][8 * s + 7]));
            u32x2 sA = __builtin_amdgcn_permlane32_swap(P0, P2, false, false);
            u32x2 sB = __builtin_amdgcn_permlane32_swap(P1, P3, false, false);
            pu[2 * kt + s] = (u32x4){sA[0], sB[0], sA[1], sB[1]};
        }
    }

    f32x16 O[2];
#pragma unroll
    for (int dt = 0; dt < 2; ++dt) O[dt] = (f32x16)(0.f);
#pragma unroll
    for (int t = 0; t < 10; ++t) {
        int kv = kb + 16 * t + 8 * hi1;
        kv = kv < 0 ? 0 : (kv > L_ - 8 ? L_ - 8 : kv);
        s16x8 pf = __builtin_bit_cast(s16x8, pu[t]);
#pragma unroll
        for (int dt = 0; dt < 2; ++dt) {
            s16x8 vf = *(const s16x8*)(vTg + (size_t)(32 * dt + l31) * L_ + kv);
            O[dt] = __builtin_amdgcn_mfma_f32_32x32x16_bf16(vf, pf, O[dt], 0, 0, 0);
        }
    }

    __hip_bfloat16* ob = attn + (size_t)(b * L_ + qg) * D_ + h * DH;
#pragma unroll
    for (int dt = 0; dt < 2; ++dt) {
#pragma unroll
        for (int rr = 0; rr < 4; ++rr) {
            s16x4 pk4;
#pragma unroll
            for (int j = 0; j < 4; ++j) {
                __hip_bfloat16 tb = __float2bfloat16(O[dt][4 * rr + j] * inv);
                pk4[j] = *reinterpret_cast<short*>(&tb);
            }
            *(s16x4*)(ob + 32 * dt + 8 * rr + 4 * hi1) = pk4;
        }
    }
}

extern "C" void kernel_launch(void* const* d_in, const int* in_sizes, int n_in,
                              void* d_out, int out_size, void* d_ws, size_t ws_size,
                              hipStream_t stream) {
    const float* x      = (const float*)d_in[0];
    const float* w_norm = (const float*)d_in[1];
    const float* w_qkv  = (const float*)d_in[2];
    const float* w_out  = (const float*)d_in[3];

    char* ws = (char*)d_ws;
    __hip_bfloat16* xn   = (__hip_bfloat16*)(ws);                        //  8 MiB
    __hip_bfloat16* wq   = (__hip_bfloat16*)(ws + (8u  << 20));          //  6 MiB
    __hip_bfloat16* wo   = (__hip_bfloat16*)(ws + (14u << 20));          //  2 MiB
    __hip_bfloat16* qkv  = (__hip_bfloat16*)(ws + (16u << 20));          // 24 MiB (q,k used)
    __hip_bfloat16* attn = (__hip_bfloat16*)(ws + (40u << 20));          //  8 MiB
    __hip_bfloat16* vT   = (__hip_bfloat16*)(ws + (48u << 20));          //  8 MiB
    float* out = (float*)d_out;

    // fused weight conversion + RMSNorm
    prep_kernel<<<1024 + M_ROWS / 4, 256, 0, stream>>>(x, w_norm, w_qkv, w_out, xn, wq, wo);

    // QKV GEMM: [4096,1024] x [3072,1024]^T -> q,k bf16 + vT transposed (128^2, 3 blocks/CU)
    gemm_qkv_kernel<<<dim3(QKV_N / 128, M_ROWS / 128), 256, 0, stream>>>(
        xn, wq, qkv, vT, M_ROWS, QKV_N, D_);

    // MFMA banded attention -> bf16 [4096,1024]
    attn_mfma_kernel<<<dim3(L_ / 64, H_, B_), 128, 0, stream>>>(qkv, vT, attn);

    // out proj + residual: [4096,1024] x [1024,1024]^T + x -> f32 d_out
    gemm_proj_kernel<<<dim3(D_ / 64, M_ROWS / 128), 256, 0, stream>>>(
        attn, wo, out, x, M_ROWS, D_, D_);
}

// Round 15
// 86.667 us; speedup vs baseline: 1.0149x; 1.0149x over previous
//
#include <hip/hip_runtime.h>
#include <hip/hip_bf16.h>
#include <cstdint>

typedef float f32x4 __attribute__((ext_vector_type(4)));
typedef float f32x16 __attribute__((ext_vector_type(16)));
typedef short s16x8 __attribute__((ext_vector_type(8)));
typedef short s16x4 __attribute__((ext_vector_type(4)));
typedef unsigned int u32x2 __attribute__((ext_vector_type(2)));
typedef unsigned int u32x4 __attribute__((ext_vector_type(4)));

constexpr int B_ = 2, L_ = 2048, D_ = 1024, H_ = 16, DH = 64, HALF = 64;
constexpr int M_ROWS = B_ * L_;   // 4096
constexpr int QKV_N = 3 * D_;     // 3072

__device__ __forceinline__ void gload16(const void* g, void* l) {
    __builtin_amdgcn_global_load_lds(
        (const __attribute__((address_space(1))) unsigned int*)g,
        (__attribute__((address_space(3))) unsigned int*)l, 16, 0, 0);
}

__device__ __forceinline__ void cfence() {
    __builtin_amdgcn_sched_barrier(0);
    asm volatile("" ::: "memory");
}

// ---------------- fused prep (r14): weight cvt 64B/thread (blocks 0..1023) + RMSNorm ----------------
__global__ __launch_bounds__(256) void prep_kernel(const float* __restrict__ x,
                                                   const float* __restrict__ wn,
                                                   const float* __restrict__ wq,
                                                   const float* __restrict__ wo,
                                                   __hip_bfloat16* __restrict__ xn,
                                                   __hip_bfloat16* __restrict__ oq,
                                                   __hip_bfloat16* __restrict__ oo) {
    constexpr int NQ16 = QKV_N * D_ / 16;            // 196608
    constexpr int NCVT16 = NQ16 + D_ * D_ / 16;      // 262144
    constexpr int CVTBLK = NCVT16 / 256;             // 1024
    int bid = blockIdx.x;
    int tid = threadIdx.x;
    if (bid < CVTBLK) {
        int i = bid * 256 + tid;
        const float* src; __hip_bfloat16* dst; int j;
        if (i < NQ16) { src = wq; dst = oq; j = i; }
        else          { src = wo; dst = oo; j = i - NQ16; }
        const float4* s4 = reinterpret_cast<const float4*>(src) + (size_t)j * 4;
        float4 v[4];
#pragma unroll
        for (int c = 0; c < 4; ++c) v[c] = s4[c];
        s16x8 p0, p1;
#pragma unroll
        for (int c = 0; c < 2; ++c) {
            float vals[8] = {v[2*c].x, v[2*c].y, v[2*c].z, v[2*c].w,
                             v[2*c+1].x, v[2*c+1].y, v[2*c+1].z, v[2*c+1].w};
            s16x8 pk;
#pragma unroll
            for (int e = 0; e < 8; ++e) {
                __hip_bfloat16 t = __float2bfloat16(vals[e]);
                pk[e] = *reinterpret_cast<short*>(&t);
            }
            if (c == 0) p0 = pk; else p1 = pk;
        }
        __hip_bfloat16* o = dst + (size_t)j * 16;
        *(s16x8*)(o) = p0;
        *(s16x8*)(o + 8) = p1;
    } else {
        int w = tid >> 6, lane = tid & 63;
        int row = (bid - CVTBLK) * 4 + w;
        const float4* xr = reinterpret_cast<const float4*>(x + (size_t)row * D_);
        const float4* wr = reinterpret_cast<const float4*>(wn);
        float4 v[4];
        float ss = 0.f;
#pragma unroll
        for (int c = 0; c < 4; ++c) {
            v[c] = xr[c * 64 + lane];
            ss += v[c].x * v[c].x + v[c].y * v[c].y + v[c].z * v[c].z + v[c].w * v[c].w;
        }
#pragma unroll
        for (int off = 32; off; off >>= 1) ss += __shfl_xor(ss, off);
        float rinv = rsqrtf(ss * (1.0f / D_) + 1e-6f);
#pragma unroll
        for (int c = 0; c < 4; ++c) {
            float4 wv = wr[c * 64 + lane];
            s16x4 pk;
            float vals[4] = {v[c].x * rinv * wv.x, v[c].y * rinv * wv.y,
                             v[c].z * rinv * wv.z, v[c].w * rinv * wv.w};
#pragma unroll
            for (int e = 0; e < 4; ++e) {
                __hip_bfloat16 t = __float2bfloat16(vals[e]);
                pk[e] = *reinterpret_cast<short*>(&t);
            }
            *(s16x4*)(xn + (size_t)row * D_ + (c * 64 + lane) * 4) = pk;
        }
    }
}

// ---------------- pipelined GEMM (r8, best measured): C[M,N] = A[M,K] * Bt[N,K]^T ----------------
// 256 thr = 4 waves (2x2); block tile 128 x BN, BK=64; counted-vmcnt double buffer.
// Per K-tile: stage kt+1 -> vmcnt(own kt retired) -> s_barrier -> cfence -> ds_read
// -> 32 MFMA -> lgkmcnt(0) -> s_barrier -> cfence.
// EPI 0 (QKV, BN=128): q,k cols -> Cbf; v cols -> LDS transpose -> vT 16B stores.
// EPI 1 (BN=64): store f32 + residual to Cf.
template <int EPI, int BN>
__global__ __launch_bounds__(256, 2) void gemm_pipe_kernel(const __hip_bfloat16* __restrict__ A,
                                                           const __hip_bfloat16* __restrict__ Bt,
                                                           __hip_bfloat16* __restrict__ Cbf,
                                                           __hip_bfloat16* __restrict__ vT,
                                                           float* __restrict__ Cf,
                                                           const float* __restrict__ resid,
                                                           int M, int N, int K) {
    constexpr int BM = 128;
    constexpr int NFR = BN / 32;
    constexpr int ABYTES = BM * 128;
    constexpr int BBYTES = BN * 128;
    constexpr int BUF = ABYTES + BBYTES;
    constexpr int AISS = BM / 32, BISS = BN / 32, NISS = AISS + BISS;
    __shared__ __align__(16) char smem[2 * BUF];

    const int tid = threadIdx.x;
    const int lane = tid & 63;
    const int wid = tid >> 6;

    int nwg = gridDim.x * gridDim.y;
    int lin = blockIdx.y * gridDim.x + blockIdx.x;
    int cpx = nwg >> 3;
    int swz = (lin & 7) * cpx + (lin >> 3);
    int bx = swz % gridDim.x;
    int by = swz / gridDim.x;

    const int rowBase = by * BM;
    const int colBase = bx * BN;
    const int NTILES = K >> 6;

    const int srow = tid >> 3;
    const int colSw = ((tid & 7) ^ (srow & 7)) << 3;
    const __hip_bfloat16* aG = A + (size_t)(rowBase + srow) * K + colSw;
    const __hip_bfloat16* bG = Bt + (size_t)(colBase + srow) * K + colSw;
    const int dstW = wid << 10;

    const int wm = wid >> 1, wn = wid & 1;
    const int l15 = lane & 15, hi = lane >> 4;
    const int s7 = l15 & 7;
    const int rA = wm * 64 + l15;
    const int rB = wn * (BN / 2) + l15;

    f32x4 acc[4][NFR];
#pragma unroll
    for (int m = 0; m < 4; ++m)
#pragma unroll
        for (int n = 0; n < NFR; ++n) acc[m][n] = (f32x4){0.f, 0.f, 0.f, 0.f};

#pragma unroll
    for (int i = 0; i < AISS; ++i) gload16(aG + (size_t)(i * 32) * K, smem + i * 4096 + dstW);
#pragma unroll
    for (int i = 0; i < BISS; ++i) gload16(bG + (size_t)(i * 32) * K, smem + ABYTES + i * 4096 + dstW);

    for (int kt = 0; kt < NTILES; ++kt) {
        const int bf = kt & 1;
        if (kt + 1 < NTILES) {
            char* base = smem + (bf ^ 1) * BUF;
            const __hip_bfloat16* as = aG + (size_t)(kt + 1) * 64;
            const __hip_bfloat16* bs = bG + (size_t)(kt + 1) * 64;
#pragma unroll
            for (int i = 0; i < AISS; ++i) gload16(as + (size_t)(i * 32) * K, base + i * 4096 + dstW);
#pragma unroll
            for (int i = 0; i < BISS; ++i) gload16(bs + (size_t)(i * 32) * K, base + ABYTES + i * 4096 + dstW);
            if constexpr (NISS == 8)
                asm volatile("s_waitcnt vmcnt(8)" ::: "memory");
            else
                asm volatile("s_waitcnt vmcnt(6)" ::: "memory");
        } else {
            asm volatile("s_waitcnt vmcnt(0)" ::: "memory");
        }
        __builtin_amdgcn_s_barrier();
        cfence();

        const char* ab = smem + bf * BUF;
        const char* bb = ab + ABYTES;
        s16x8 af[4][2], bfr[NFR][2];
#pragma unroll
        for (int mf = 0; mf < 4; ++mf)
#pragma unroll
            for (int kk = 0; kk < 2; ++kk)
                af[mf][kk] = *(const s16x8*)(ab + (rA + mf * 16) * 128 + (((kk * 4 + hi) ^ s7) << 4));
#pragma unroll
        for (int nf = 0; nf < NFR; ++nf)
#pragma unroll
            for (int kk = 0; kk < 2; ++kk)
                bfr[nf][kk] = *(const s16x8*)(bb + (rB + nf * 16) * 128 + (((kk * 4 + hi) ^ s7) << 4));

        __builtin_amdgcn_s_setprio(1);
#pragma unroll
        for (int kk = 0; kk < 2; ++kk)
#pragma unroll
            for (int mf = 0; mf < 4; ++mf)
#pragma unroll
                for (int nf = 0; nf < NFR; ++nf)
                    acc[mf][nf] = __builtin_amdgcn_mfma_f32_16x16x32_bf16(af[mf][kk], bfr[nf][kk],
                                                                          acc[mf][nf], 0, 0, 0);
        __builtin_amdgcn_s_setprio(0);

        asm volatile("s_waitcnt lgkmcnt(0)" ::: "memory");
        __builtin_amdgcn_s_barrier();
        cfence();
    }

    if constexpr (EPI == 0) {
        if (colBase < 2 * D_) {
#pragma unroll
            for (int mf = 0; mf < 4; ++mf)
#pragma unroll
                for (int nf = 0; nf < NFR; ++nf) {
                    int col = colBase + wn * (BN / 2) + nf * 16 + l15;
                    int row0 = rowBase + wm * 64 + mf * 16 + 4 * hi;
#pragma unroll
                    for (int r = 0; r < 4; ++r)
                        Cbf[(size_t)(row0 + r) * N + col] = __float2bfloat16(acc[mf][nf][r]);
                }
        } else {
            char* Ct = smem;
#pragma unroll
            for (int mf = 0; mf < 4; ++mf)
#pragma unroll
                for (int nf = 0; nf < NFR; ++nf) {
                    int cl = wn * (BN / 2) + nf * 16 + l15;
#pragma unroll
                    for (int r = 0; r < 4; ++r) {
                        int rl = wm * 64 + mf * 16 + 4 * hi + r;
                        __hip_bfloat16 t = __float2bfloat16(acc[mf][nf][r]);
                        *(short*)(Ct + cl * 272 + rl * 2) = *reinterpret_cast<short*>(&t);
                    }
                }
            __syncthreads();
            int cl = tid >> 1, half = tid & 1;
            int gcol = colBase + cl - 2 * D_;
            int hh = gcol >> 6, dd = gcol & 63;
            int bb2 = rowBase >> 11, i0 = rowBase & (L_ - 1);
            __hip_bfloat16* dstp = vT + ((size_t)(bb2 * H_ + hh) * DH + dd) * L_ + i0 + half * 64;
#pragma unroll
            for (int ch = 0; ch < 8; ++ch) {
                s16x8 vv = *(const s16x8*)(Ct + cl * 272 + half * 128 + ch * 16);
                *(s16x8*)(dstp + ch * 8) = vv;
            }
        }
    } else {
#pragma unroll
        for (int mf = 0; mf < 4; ++mf)
#pragma unroll
            for (int nf = 0; nf < NFR; ++nf) {
                int col = colBase + wn * (BN / 2) + nf * 16 + l15;
                int row0 = rowBase + wm * 64 + mf * 16 + 4 * hi;
#pragma unroll
                for (int r = 0; r < 4; ++r)
                    Cf[(size_t)(row0 + r) * N + col] = acc[mf][nf][r] + resid[(size_t)(row0 + r) * N + col];
            }
    }
}

// ---------------- barrier-free LDS-free MFMA banded attention (round-8, proven) ----------------
__global__ __launch_bounds__(128, 2) void attn_mfma_kernel(const __hip_bfloat16* __restrict__ qkv,
                                                           const __hip_bfloat16* __restrict__ vT,
                                                           __hip_bfloat16* __restrict__ attn) {
    int tid = threadIdx.x;
    int w = tid >> 6;
    int lane = tid & 63;
    int l31 = lane & 31, hi1 = lane >> 5;
    int tq = blockIdx.x, h = blockIdx.y, b = blockIdx.z;
    int qbase = tq * 64 + 32 * w;
    int kb = qbase - HALF;
    int qg = qbase + l31;
    const __hip_bfloat16* qkvb = qkv + (size_t)(b * L_) * QKV_N;
    const __hip_bfloat16* vTg = vT + (size_t)(b * H_ + h) * DH * L_;

    s16x8 qf[4];
#pragma unroll
    for (int kk = 0; kk < 4; ++kk)
        qf[kk] = *(const s16x8*)(qkvb + (size_t)qg * QKV_N + h * DH + kk * 16 + hi1 * 8);

    f32x16 T[5];
#pragma unroll
    for (int kt = 0; kt < 5; ++kt) T[kt] = (f32x16)(0.f);
#pragma unroll
    for (int kt = 0; kt < 5; ++kt) {
        int keyg = kb + 32 * kt + l31;
        int kc = keyg < 0 ? 0 : (keyg > L_ - 1 ? L_ - 1 : keyg);
        const __hip_bfloat16* kp = qkvb + (size_t)kc * QKV_N + D_ + h * DH + hi1 * 8;
#pragma unroll
        for (int kk = 0; kk < 4; ++kk) {
            s16x8 kf = *(const s16x8*)(kp + kk * 16);
            T[kt] = __builtin_amdgcn_mfma_f32_32x32x16_bf16(kf, qf[kk], T[kt], 0, 0, 0);
        }
    }

    float mx = -1e30f;
#pragma unroll
    for (int kt = 0; kt < 5; ++kt) {
#pragma unroll
        for (int r = 0; r < 16; ++r) {
            int koff = (r & 3) + 8 * (r >> 2) + 4 * hi1;
            int keyg = kb + 32 * kt + koff;
            int del = keyg - qg;
            bool ok = (del >= -HALF) && (del <= HALF) && (keyg >= 0) && (keyg < L_);
            float t = ok ? T[kt][r] * 0.125f : -1e30f;
            T[kt][r] = t;
            mx = fmaxf(mx, t);
        }
    }
    mx = fmaxf(mx, __shfl_xor(mx, 32));
    float sum = 0.f;
#pragma unroll
    for (int kt = 0; kt < 5; ++kt) {
#pragma unroll
        for (int r = 0; r < 16; ++r) {
            float p = __expf(T[kt][r] - mx);
            T[kt][r] = p;
            sum += p;
        }
    }
    sum += __shfl_xor(sum, 32);
    float inv = 1.0f / sum;

    u32x4 pu[10];
#pragma unroll
    for (int kt = 0; kt < 5; ++kt) {
#pragma unroll
        for (int s = 0; s < 2; ++s) {
            unsigned P0, P1, P2, P3;
            asm("v_cvt_pk_bf16_f32 %0, %1, %2" : "=v"(P0) : "v"(T[kt][8 * s + 0]), "v"(T[kt][8 * s + 1]));
            asm("v_cvt_pk_bf16_f32 %0, %1, %2" : "=v"(P1) : "v"(T[kt][8 * s + 2]), "v"(T[kt][8 * s + 3]));
            asm("v_cvt_pk_bf16_f32 %0, %1, %2" : "=v"(P2) : "v"(T[kt][8 * s + 4]), "v"(T[kt][8 * s + 5]));
            asm("v_cvt_pk_bf16_f32 %0, %1, %2" : "=v"(P3) : "v"(T[kt][8 * s + 6]), "v"(T[kt][8 * s + 7]));
            u32x2 sA = __builtin_amdgcn_permlane32_swap(P0, P2, false, false);
            u32x2 sB = __builtin_amdgcn_permlane32_swap(P1, P3, false, false);
            pu[2 * kt + s] = (u32x4){sA[0], sB[0], sA[1], sB[1]};
        }
    }

    f32x16 O[2];
#pragma unroll
    for (int dt = 0; dt < 2; ++dt) O[dt] = (f32x16)(0.f);
#pragma unroll
    for (int t = 0; t < 10; ++t) {
        int kv = kb + 16 * t + 8 * hi1;
        kv = kv < 0 ? 0 : (kv > L_ - 8 ? L_ - 8 : kv);
        s16x8 pf = __builtin_bit_cast(s16x8, pu[t]);
#pragma unroll
        for (int dt = 0; dt < 2; ++dt) {
            s16x8 vf = *(const s16x8*)(vTg + (size_t)(32 * dt + l31) * L_ + kv);
            O[dt] = __builtin_amdgcn_mfma_f32_32x32x16_bf16(vf, pf, O[dt], 0, 0, 0);
        }
    }

    __hip_bfloat16* ob = attn + (size_t)(b * L_ + qg) * D_ + h * DH;
#pragma unroll
    for (int dt = 0; dt < 2; ++dt) {
#pragma unroll
        for (int rr = 0; rr < 4; ++rr) {
            s16x4 pk4;
#pragma unroll
            for (int j = 0; j < 4; ++j) {
                __hip_bfloat16 tb = __float2bfloat16(O[dt][4 * rr + j] * inv);
                pk4[j] = *reinterpret_cast<short*>(&tb);
            }
            *(s16x4*)(ob + 32 * dt + 8 * rr + 4 * hi1) = pk4;
        }
    }
}

extern "C" void kernel_launch(void* const* d_in, const int* in_sizes, int n_in,
                              void* d_out, int out_size, void* d_ws, size_t ws_size,
                              hipStream_t stream) {
    const float* x      = (const float*)d_in[0];
    const float* w_norm = (const float*)d_in[1];
    const float* w_qkv  = (const float*)d_in[2];
    const float* w_out  = (const float*)d_in[3];

    char* ws = (char*)d_ws;
    __hip_bfloat16* xn   = (__hip_bfloat16*)(ws);                        //  8 MiB
    __hip_bfloat16* wq   = (__hip_bfloat16*)(ws + (8u  << 20));          //  6 MiB
    __hip_bfloat16* wo   = (__hip_bfloat16*)(ws + (14u << 20));          //  2 MiB
    __hip_bfloat16* qkv  = (__hip_bfloat16*)(ws + (16u << 20));          // 24 MiB (q,k used)
    __hip_bfloat16* attn = (__hip_bfloat16*)(ws + (40u << 20));          //  8 MiB
    __hip_bfloat16* vT   = (__hip_bfloat16*)(ws + (48u << 20));          //  8 MiB
    float* out = (float*)d_out;

    // fused weight conversion + RMSNorm (r14 vectorized prep)
    prep_kernel<<<1024 + M_ROWS / 4, 256, 0, stream>>>(x, w_norm, w_qkv, w_out, xn, wq, wo);

    // QKV GEMM: [4096,1024] x [3072,1024]^T -> q,k bf16 + vT transposed (r8 best)
    gemm_pipe_kernel<0, 128><<<dim3(QKV_N / 128, M_ROWS / 128), 256, 0, stream>>>(
        xn, wq, qkv, vT, nullptr, nullptr, M_ROWS, QKV_N, D_);

    // MFMA banded attention -> bf16 [4096,1024]
    attn_mfma_kernel<<<dim3(L_ / 64, H_, B_), 128, 0, stream>>>(qkv, vT, attn);

    // out proj + residual: [4096,1024] x [1024,1024]^T + x -> f32 d_out (r8 best)
    gemm_pipe_kernel<1, 64><<<dim3(D_ / 64, M_ROWS / 128), 256, 0, stream>>>(
        attn, wo, nullptr, nullptr, out, x, M_ROWS, D_, D_);
}